// Round 8
// baseline (187.378 us; speedup 1.0000x reference)
//
#include <hip/hip_runtime.h>
#include <math.h>

// AutoregressiveFlowLayer MI355X — round 8.
// R7 post-mortem: 83us rocprof; VALU 29.5% (perm-tax removal worked), LDS ~50%,
// MFMA 21.5% — all pipes <=50%, so ~40% is barrier serialization that the
// 2-barrier/tile x 2-block/CU structure can't hide. Structure is forced 4-wave
// (B2 frags for 64 cols = 128 VGPRs = occupancy cliff), so traffic can't shrink;
// attack the barrier structure instead.
// R8: ONE barrier per tile, depth-4 pipeline, 1 block/CU (grid 256, 32 tiles):
//   interval(t) = store(t-2) | gather(t+2) | P2(t) | P3(t-1)+epi(t-1) | P1(t+1)
// Buffering: h1[2], h2[2], xgh/xgl[2], xgf[4], red[2].
// Hazard table (all pairs barrier-separated):
//   h1[b]: written P1(t+1)@I(t), read P2(t+1)@I(t+1).
//   h2[b]: written P2(t)@I(t), read P3(t)@I(t+1); next write P2(t+2)@I(t+2).
//   xgh/l[b]: written gather(t+2)@I(t), read P1(t+2)@I(t+1); prior reader P1(t)@I(t-1).
//   xgf[b4]: written gather(t+2)@I(t), read epi(t+2)@I(t+3); next write @I(t+4).
//   red[b]: written epi(t-1)@I(t), read store(t-1)@I(t+1); next write epi(t+1)@I(t+2).
// 1 block/CU: per-CU LDS traffic unchanged (32 tiles x 4 waves), barrier events
// halved, intervals mix 4 tiles' work (MFMA+LDS+global+VALU) for deep ILP; at
// 1 wave/SIMD the register file is 512/wave so the R4/R5 pressure constraint is gone.
// Kept: weights staged via LDS scratch into register frags (R4: direct global->reg
// spills); hi/lo planes + truncated residual (R7).

#define RR 32
#define DD 1024
#define HH 128
#define OO 64
#define TROWS 32
#define TILES 32
#define BLOCKS_PER_R 8

#define SHP 136   // u16 stride, h planes
#define SXG 40    // u16 stride, xg planes
#define SXF 33    // f32 stride, xgf
#define SSC 132   // u32 scratch stride (W2/Wout staging)
#define SW1 36    // u32 scratch stride (W1 staging)

typedef short bf16x8_t __attribute__((ext_vector_type(8)));
typedef float f32x4_t __attribute__((ext_vector_type(4)));
typedef unsigned short u16;
typedef unsigned int u32;

__device__ __forceinline__ u16 bf16_rne(float x) {
    u32 u = __float_as_uint(x);
    u += 0x7FFFu + ((u >> 16) & 1u);
    return (u16)(u >> 16);
}
__device__ __forceinline__ float bf16_tof(u16 h) {
    return __uint_as_float(((u32)h) << 16);
}
__device__ __forceinline__ u16 lo_trunc(float v, u16 h) {
    return (u16)(__float_as_uint(v - bf16_tof(h)) >> 16);
}
__device__ __forceinline__ u32 pack_split(float v) {
    u16 h = bf16_rne(v);
    return (u32)h | ((u32)lo_trunc(v, h) << 16);
}
__device__ __forceinline__ void unpack8(const u32* p, bf16x8_t& hi, bf16x8_t& lo) {
    uint4 a = *reinterpret_cast<const uint4*>(p);
    uint4 b = *reinterpret_cast<const uint4*>(p + 4);
    union { u32 u[4]; bf16x8_t v; } H, L;
    H.u[0] = __builtin_amdgcn_perm(a.y, a.x, 0x05040100u);
    H.u[1] = __builtin_amdgcn_perm(a.w, a.z, 0x05040100u);
    H.u[2] = __builtin_amdgcn_perm(b.y, b.x, 0x05040100u);
    H.u[3] = __builtin_amdgcn_perm(b.w, b.z, 0x05040100u);
    L.u[0] = __builtin_amdgcn_perm(a.y, a.x, 0x07060302u);
    L.u[1] = __builtin_amdgcn_perm(a.w, a.z, 0x07060302u);
    L.u[2] = __builtin_amdgcn_perm(b.y, b.x, 0x07060302u);
    L.u[3] = __builtin_amdgcn_perm(b.w, b.z, 0x07060302u);
    hi = H.v; lo = L.v;
}
__device__ __forceinline__ f32x4_t mfma16(bf16x8_t a, bf16x8_t b, f32x4_t c) {
    return __builtin_amdgcn_mfma_f32_16x16x32_bf16(a, b, c, 0, 0, 0);
}

// stage [K x 32] weight slice -> packed-dword [col][k] scratch, conflict-free
__device__ __forceinline__ void stage_block(const float* __restrict__ W,
                                            const int* __restrict__ M,
                                            int ldc, int c0, int K, u32* dst, int sd,
                                            int tid)
{
    const int kb = tid >> 3;
    const int cb = tid & 7;
    if (kb * 4 >= K) return;
    const int k0 = kb * 4;
    float e[4][4];
#pragma unroll
    for (int i = 0; i < 4; ++i) {
        const int o = ((k0 + i) * ldc + c0 + 4 * cb) >> 2;
        float4 w = ((const float4*)W)[o];
        int4   m = ((const int4*)M)[o];
        e[i][0] = m.x ? w.x : 0.f; e[i][1] = m.y ? w.y : 0.f;
        e[i][2] = m.z ? w.z : 0.f; e[i][3] = m.w ? w.w : 0.f;
    }
#pragma unroll
    for (int j = 0; j < 4; ++j) {
        uint4 p;
        p.x = pack_split(e[0][j]); p.y = pack_split(e[1][j]);
        p.z = pack_split(e[2][j]); p.w = pack_split(e[3][j]);
        *(uint4*)&dst[(4 * cb + j) * sd + k0] = p;
    }
}

__global__ __launch_bounds__(256, 1)
void made_flow_r8(const float* __restrict__ inputs,
                  const float* __restrict__ W1,
                  const float* __restrict__ W2,
                  const float* __restrict__ Wout,
                  const int* __restrict__ idx,
                  const int* __restrict__ valid,
                  const int* __restrict__ M1,
                  const int* __restrict__ M2,
                  const int* __restrict__ Mout,
                  float* __restrict__ out)
{
    // bufH1[b] = h1 hi plane (8704 B) then lo plane; bufH1 also hosts preamble scratch.
    __shared__ __align__(16) char bufH1[2][TROWS * SHP * 2 * 2];   // 34816 B
    __shared__ __align__(16) char bufH2[2][TROWS * SHP * 2 * 2];   // 34816 B
    __shared__ __align__(16) u16  xgh[2][TROWS * SXG];             // 5120 B
    __shared__ __align__(16) u16  xgl[2][TROWS * SXG];             // 5120 B
    __shared__ float xgf[4][TROWS * SXF];                          // 16896 B
    __shared__ float red[2][TROWS * 4];                            // 1024 B
    __shared__ int   idx_s[RR];
    __shared__ float v_s[RR];

    u32* const scr   = (u32*)bufH1[0];   // 16896 B <= 17408
    u32* const scrW1 = (u32*)bufH1;      // 18432 B <= 34816 (W1 round)

    const int tid  = threadIdx.x;
    const int r    = blockIdx.x / BLOCKS_PER_R;
    const int rb   = blockIdx.x % BLOCKS_PER_R;
    const int lane = tid & 63;
    const int wave = tid >> 6;
    const int q    = lane >> 4;
    const int l16  = lane & 15;
    const int nb   = 2 * wave;

    if (tid < RR) {
        idx_s[tid] = idx[r * RR + tid];
        v_s[tid]   = valid[r * RR + tid] ? 1.f : 0.f;
    }

    // ---- stage all weights -> per-wave register frags via LDS scratch ----
    bf16x8_t b1h[2], b1l[2];
    bf16x8_t b2h[2][4], b2l[2][4];
    bf16x8_t boh[4],    bol[4];
    {
        const float* W1r = W1 + r * RR * HH;   const int* M1r = M1 + r * RR * HH;
        const float* W2r = W2 + r * HH * HH;   const int* M2r = M2 + r * HH * HH;
        const float* Wor = Wout + r * HH * OO; const int* Mor = Mout + r * HH * OO;
        for (int c = 0; c < 4; ++c) {
            __syncthreads();
            stage_block(W2r, M2r, HH, 32 * c, HH, scr, SSC, tid);
            __syncthreads();
            if (wave == c) {
#pragma unroll
                for (int ni = 0; ni < 2; ++ni)
#pragma unroll
                    for (int ks = 0; ks < 4; ++ks)
                        unpack8(&scr[(16 * ni + l16) * SSC + ks * 32 + q * 8],
                                b2h[ni][ks], b2l[ni][ks]);
            }
        }
        for (int c = 0; c < 2; ++c) {
            __syncthreads();
            stage_block(Wor, Mor, OO, 32 * c, HH, scr, SSC, tid);
            __syncthreads();
            if ((wave >> 1) == c) {
                const int nl = wave & 1;
#pragma unroll
                for (int ks = 0; ks < 4; ++ks)
                    unpack8(&scr[(16 * nl + l16) * SSC + ks * 32 + q * 8],
                            boh[ks], bol[ks]);
            }
        }
        // W1: one full-width round (128 cols x 32 k), all 256 threads
        __syncthreads();
        {
            const int cb = tid & 31, kb = tid >> 5;
            const int k0 = kb * 4, c0 = cb * 4;
            float e[4][4];
#pragma unroll
            for (int i = 0; i < 4; ++i) {
                const int o = ((k0 + i) * HH + c0) >> 2;
                float4 w = ((const float4*)W1r)[o];
                int4   m = ((const int4*)M1r)[o];
                e[i][0] = m.x ? w.x : 0.f; e[i][1] = m.y ? w.y : 0.f;
                e[i][2] = m.z ? w.z : 0.f; e[i][3] = m.w ? w.w : 0.f;
            }
#pragma unroll
            for (int j = 0; j < 4; ++j) {
                uint4 p;
                p.x = pack_split(e[0][j]); p.y = pack_split(e[1][j]);
                p.z = pack_split(e[2][j]); p.w = pack_split(e[3][j]);
                *(uint4*)&scrW1[(c0 + j) * SW1 + k0] = p;
            }
        }
        __syncthreads();
#pragma unroll
        for (int ni = 0; ni < 2; ++ni)
            unpack8(&scrW1[(16 * (nb + ni) + l16) * SW1 + q * 8], b1h[ni], b1l[ni]);
    }
    __syncthreads();   // all scratch reads done

    const f32x4_t zero4 = {0.f, 0.f, 0.f, 0.f};
    const int grow = tid >> 3, gg = tid & 7;

    // ---- prologue: gather(0), gather(1) ----
#pragma unroll
    for (int tt = 0; tt < 2; ++tt) {
        const int base = ((rb * TILES + tt) * TROWS + grow) * DD;
#pragma unroll
        for (int u = 0; u < 4; ++u) {
            const float x = inputs[base + idx_s[4 * gg + u]] * v_s[4 * gg + u];
            const u16 h = bf16_rne(x);
            xgh[tt][grow * SXG + 4 * gg + u] = h;
            xgl[tt][grow * SXG + 4 * gg + u] = lo_trunc(x, h);
            xgf[tt][grow * SXF + 4 * gg + u] = x;
        }
    }
    __syncthreads();

    // ---- prologue: P1(0) ----
    {
        u16* const h1hb = (u16*)bufH1[0];
        u16* const h1lb = h1hb + TROWS * SHP;
        bf16x8_t ah[2], al[2];
#pragma unroll
        for (int mi = 0; mi < 2; ++mi) {
            ah[mi] = *(const bf16x8_t*)&xgh[0][(16 * mi + l16) * SXG + q * 8];
            al[mi] = *(const bf16x8_t*)&xgl[0][(16 * mi + l16) * SXG + q * 8];
        }
        f32x4_t a1[2][2];
#pragma unroll
        for (int ni = 0; ni < 2; ++ni)
#pragma unroll
            for (int mi = 0; mi < 2; ++mi) {
                f32x4_t a = zero4;
                a = mfma16(ah[mi], b1h[ni], a);
                a = mfma16(al[mi], b1h[ni], a);
                a = mfma16(ah[mi], b1l[ni], a);
                a1[mi][ni] = a;
            }
#pragma unroll
        for (int mi = 0; mi < 2; ++mi)
#pragma unroll
            for (int ni = 0; ni < 2; ++ni)
#pragma unroll
                for (int i = 0; i < 4; ++i) {
                    const int o = (16 * mi + 4 * q + i) * SHP + 16 * (nb + ni) + l16;
                    const float v = fmaxf(a1[mi][ni][i], 0.f);
                    const u16 h = bf16_rne(v);
                    h1hb[o] = h;
                    h1lb[o] = lo_trunc(v, h);
                }
    }

    // ================== main pipeline: ONE barrier per interval ==================
    for (int t = 0; t <= TILES + 1; ++t) {
        __syncthreads();

        // ---- deferred store(t-2) ----
        if (t >= 2 && tid < TROWS) {
            float4 rv = *(const float4*)&red[(t - 2) & 1][tid * 4];
            out[((rb * TILES + (t - 2)) * TROWS + tid) * RR + r] =
                rv.x + rv.y + rv.z + rv.w;
        }

        // ---- gather(t+2): issue global loads early ----
        float gx[4];
        const bool dg = (t + 2 < TILES);
        if (dg) {
            const int base = ((rb * TILES + t + 2) * TROWS + grow) * DD;
#pragma unroll
            for (int u = 0; u < 4; ++u)
                gx[u] = inputs[base + idx_s[4 * gg + u]] * v_s[4 * gg + u];
        }

        // ---- P2(t): h2[t&1] = relu(h1[t&1] @ W2m) ----
        if (t < TILES) {
            const u16* h1hb = (const u16*)bufH1[t & 1];
            const u16* h1lb = h1hb + TROWS * SHP;
            u16* const h2hb = (u16*)bufH2[t & 1];
            u16* const h2lb = h2hb + TROWS * SHP;
            f32x4_t acc[2][2] = {{zero4, zero4}, {zero4, zero4}};
#pragma unroll
            for (int ks = 0; ks < 4; ++ks) {
#pragma unroll
                for (int mi = 0; mi < 2; ++mi) {
                    bf16x8_t ah = *(const bf16x8_t*)&h1hb[(16 * mi + l16) * SHP + ks * 32 + q * 8];
                    bf16x8_t al = *(const bf16x8_t*)&h1lb[(16 * mi + l16) * SHP + ks * 32 + q * 8];
#pragma unroll
                    for (int ni = 0; ni < 2; ++ni) {
                        f32x4_t a = acc[mi][ni];
                        a = mfma16(ah, b2h[ni][ks], a);
                        a = mfma16(al, b2h[ni][ks], a);
                        a = mfma16(ah, b2l[ni][ks], a);
                        acc[mi][ni] = a;
                    }
                }
            }
#pragma unroll
            for (int mi = 0; mi < 2; ++mi)
#pragma unroll
                for (int ni = 0; ni < 2; ++ni)
#pragma unroll
                    for (int i = 0; i < 4; ++i) {
                        const int o = (16 * mi + 4 * q + i) * SHP + 16 * (nb + ni) + l16;
                        const float v = fmaxf(acc[mi][ni][i], 0.f);
                        const u16 h = bf16_rne(v);
                        h2hb[o] = h;
                        h2lb[o] = lo_trunc(v, h);
                    }
        }

        // ---- gather(t+2): store to xg buffers ----
        if (dg) {
            const int b2 = t & 1;          // == (t+2)&1
            const int b4 = (t + 2) & 3;
            ushort4 gh, gl;
            gh.x = bf16_rne(gx[0]); gl.x = lo_trunc(gx[0], gh.x);
            gh.y = bf16_rne(gx[1]); gl.y = lo_trunc(gx[1], gh.y);
            gh.z = bf16_rne(gx[2]); gl.z = lo_trunc(gx[2], gh.z);
            gh.w = bf16_rne(gx[3]); gl.w = lo_trunc(gx[3], gh.w);
            *(ushort4*)&xgh[b2][grow * SXG + 4 * gg] = gh;
            *(ushort4*)&xgl[b2][grow * SXG + 4 * gg] = gl;
#pragma unroll
            for (int u = 0; u < 4; ++u)
                xgf[b4][grow * SXF + 4 * gg + u] = gx[u];
        }

        // ---- P3(t-1) + epilogue(t-1) ----
        if (t >= 1 && t <= TILES) {
            const int tm = t - 1;
            const u16* h2hb = (const u16*)bufH2[tm & 1];
            const u16* h2lb = h2hb + TROWS * SHP;
            f32x4_t acc3[2] = {zero4, zero4};
#pragma unroll
            for (int ks = 0; ks < 4; ++ks) {
#pragma unroll
                for (int mi = 0; mi < 2; ++mi) {
                    bf16x8_t ah = *(const bf16x8_t*)&h2hb[(16 * mi + l16) * SHP + ks * 32 + q * 8];
                    bf16x8_t al = *(const bf16x8_t*)&h2lb[(16 * mi + l16) * SHP + ks * 32 + q * 8];
                    f32x4_t a = acc3[mi];
                    a = mfma16(ah, boh[ks], a);
                    a = mfma16(al, boh[ks], a);
                    a = mfma16(ah, bol[ks], a);
                    acc3[mi] = a;
                }
            }
            // epilogue: acc3[mi][i] -> row 16*mi+4*q+i, col 16*wave+l16
            const int p  = lane & 1;
            const int j  = 8 * wave + (l16 >> 1);
            const float vj = v_s[j];
            float part[4];
#pragma unroll
            for (int i = 0; i < 4; ++i) {
                float v = p ? acc3[0][i] : acc3[1][i];
                float o = __shfl_xor(v, 1, 64);
                const float sh = p ? o : acc3[0][i];
                const float ls = p ? acc3[1][i] : o;
                const float x  = xgf[tm & 3][(16 * p + 4 * q + i) * SXF + j];
                const float uu = (x - sh) * __expf(-ls);
                part[i] = (-0.5f * uu * uu - 0.91893853320467266954f - ls) * vj;
            }
#pragma unroll
            for (int m = 2; m <= 8; m <<= 1)
#pragma unroll
                for (int i = 0; i < 4; ++i)
                    part[i] += __shfl_xor(part[i], m, 64);
            if ((l16 >> 1) == 0) {
#pragma unroll
                for (int i = 0; i < 4; ++i)
                    red[tm & 1][(16 * p + 4 * q + i) * 4 + wave] = part[i];
            }
        }

        // ---- P1(t+1): h1[(t+1)&1] = relu(xg[(t+1)&1] @ W1m) ----
        if (t + 1 < TILES) {
            const int tp = t + 1;
            const u16* xh = xgh[tp & 1];
            const u16* xl = xgl[tp & 1];
            u16* const h1hb = (u16*)bufH1[tp & 1];
            u16* const h1lb = h1hb + TROWS * SHP;
            bf16x8_t ah[2], al[2];
#pragma unroll
            for (int mi = 0; mi < 2; ++mi) {
                ah[mi] = *(const bf16x8_t*)&xh[(16 * mi + l16) * SXG + q * 8];
                al[mi] = *(const bf16x8_t*)&xl[(16 * mi + l16) * SXG + q * 8];
            }
            f32x4_t a1[2][2];
#pragma unroll
            for (int ni = 0; ni < 2; ++ni)
#pragma unroll
                for (int mi = 0; mi < 2; ++mi) {
                    f32x4_t a = zero4;
                    a = mfma16(ah[mi], b1h[ni], a);
                    a = mfma16(al[mi], b1h[ni], a);
                    a = mfma16(ah[mi], b1l[ni], a);
                    a1[mi][ni] = a;
                }
#pragma unroll
            for (int mi = 0; mi < 2; ++mi)
#pragma unroll
                for (int ni = 0; ni < 2; ++ni)
#pragma unroll
                    for (int i = 0; i < 4; ++i) {
                        const int o = (16 * mi + 4 * q + i) * SHP + 16 * (nb + ni) + l16;
                        const float v = fmaxf(a1[mi][ni][i], 0.f);
                        const u16 h = bf16_rne(v);
                        h1hb[o] = h;
                        h1lb[o] = lo_trunc(v, h);
                    }
        }
    }
}

extern "C" void kernel_launch(void* const* d_in, const int* in_sizes, int n_in,
                              void* d_out, int out_size, void* d_ws, size_t ws_size,
                              hipStream_t stream)
{
    const float* inputs = (const float*)d_in[0];
    const float* W1     = (const float*)d_in[1];
    const float* W2     = (const float*)d_in[2];
    const float* Wout   = (const float*)d_in[3];
    const int*   idx    = (const int*)d_in[4];
    const int*   valid  = (const int*)d_in[5];
    const int*   M1     = (const int*)d_in[6];
    const int*   M2     = (const int*)d_in[7];
    const int*   Mout   = (const int*)d_in[8];
    float*       out    = (float*)d_out;

    hipLaunchKernelGGL(made_flow_r8, dim3(RR * BLOCKS_PER_R), dim3(256), 0, stream,
                       inputs, W1, W2, Wout, idx, valid, M1, M2, Mout, out);
}

// Round 9
// 143.627 us; speedup vs baseline: 1.3046x; 1.3046x over previous
//
#include <hip/hip_runtime.h>
#include <math.h>

// AutoregressiveFlowLayer MI355X — round 9.
// R8 post-mortem: 1-block/CU deep pipeline REGRESSED (119us) — 1 wave/SIMD can't
// hide its own stalls; TLP >= 2 waves/SIMD is mandatory. R7 (83us, 2 blocks/CU,
// 2 barriers/tile) is the proven skeleton.
// R9 = R7 skeleton + OPERAND SWAP: weights = A operand (W^T, same LDS-scratch
// staging, same registers), activations = B operand. Consequences:
//  (1) C output is h^T: 4 consecutive feature-cols per reg quad at fixed batch
//      row -> activation stores are ds_write_b64 (8/thread/phase vs 32 b16).
//      B-reads of activations stay contiguous ds_read_b128 at natural [row][feat]
//      layout (stride 136: bank-minimal, verified).
//  (2) P3 swapped C-layout: shift & log_s for 2 j's land IN-THREAD (o=16w+4q+i,
//      i even=shift, i odd=log_s, j=8w+2q+(i>>1)) — no pairing shuffle; in-wave
//      reduce = 2 shfl per ni.
//  (3) No global stores in the loop: per-tile row-sums -> red_all[16][32][4] LDS;
//      single tail write (removes vmcnt(0) store-drain at every barrier).
// Kept: weights via LDS scratch into reg frags (R4: direct global->reg spills);
// hi/lo planes + truncated lo residual (R7); 2 blocks/CU (R5/R8: reg/TLP limits).
// LDS = 63.2 KB -> 2 blocks/CU.

#define RR 32
#define DD 1024
#define HH 128
#define OO 64
#define TROWS 32
#define TILES_PER_BLOCK 16
#define BLOCKS_PER_R 16

#define SHP 136   // u16 stride, h planes [row][feat]
#define SXG 40    // u16 stride, xg planes [row][feat]
#define SXF 38    // f32 stride, xgf (6*l16 bank walk -> <=2-way epi reads)
#define SSC 132   // u32 scratch stride (weight staging)

typedef short bf16x8_t __attribute__((ext_vector_type(8)));
typedef float f32x4_t __attribute__((ext_vector_type(4)));
typedef unsigned short u16;
typedef unsigned int u32;

__device__ __forceinline__ u16 bf16_rne(float x) {
    u32 u = __float_as_uint(x);
    u += 0x7FFFu + ((u >> 16) & 1u);
    return (u16)(u >> 16);
}
__device__ __forceinline__ float bf16_tof(u16 h) {
    return __uint_as_float(((u32)h) << 16);
}
__device__ __forceinline__ u16 lo_trunc(float v, u16 h) {
    return (u16)(__float_as_uint(v - bf16_tof(h)) >> 16);
}
__device__ __forceinline__ u32 pack_split(float v) {
    u16 h = bf16_rne(v);
    return (u32)h | ((u32)lo_trunc(v, h) << 16);
}
// preamble only: 8 packed dwords -> hi/lo frags
__device__ __forceinline__ void unpack8(const u32* p, bf16x8_t& hi, bf16x8_t& lo) {
    uint4 a = *reinterpret_cast<const uint4*>(p);
    uint4 b = *reinterpret_cast<const uint4*>(p + 4);
    union { u32 u[4]; bf16x8_t v; } H, L;
    H.u[0] = __builtin_amdgcn_perm(a.y, a.x, 0x05040100u);
    H.u[1] = __builtin_amdgcn_perm(a.w, a.z, 0x05040100u);
    H.u[2] = __builtin_amdgcn_perm(b.y, b.x, 0x05040100u);
    H.u[3] = __builtin_amdgcn_perm(b.w, b.z, 0x05040100u);
    L.u[0] = __builtin_amdgcn_perm(a.y, a.x, 0x07060302u);
    L.u[1] = __builtin_amdgcn_perm(a.w, a.z, 0x07060302u);
    L.u[2] = __builtin_amdgcn_perm(b.y, b.x, 0x07060302u);
    L.u[3] = __builtin_amdgcn_perm(b.w, b.z, 0x07060302u);
    hi = H.v; lo = L.v;
}
__device__ __forceinline__ f32x4_t mfma16(bf16x8_t a, bf16x8_t b, f32x4_t c) {
    return __builtin_amdgcn_mfma_f32_16x16x32_bf16(a, b, c, 0, 0, 0);
}

// stage [K x 32] weight slice (row-major [k][col], ld ldc, col offset c0) into
// packed-dword [col][k] scratch, conflict-free 4x4 transpose.
__device__ __forceinline__ void stage_block(const float* __restrict__ W,
                                            const int* __restrict__ M,
                                            int ldc, int c0, int K, u32* dst, int sd,
                                            int tid)
{
    const int kb = tid >> 3;
    const int cb = tid & 7;
    if (kb * 4 >= K) return;
    const int k0 = kb * 4;
    float e[4][4];
#pragma unroll
    for (int i = 0; i < 4; ++i) {
        const int o = ((k0 + i) * ldc + c0 + 4 * cb) >> 2;
        float4 w = ((const float4*)W)[o];
        int4   m = ((const int4*)M)[o];
        e[i][0] = m.x ? w.x : 0.f; e[i][1] = m.y ? w.y : 0.f;
        e[i][2] = m.z ? w.z : 0.f; e[i][3] = m.w ? w.w : 0.f;
    }
#pragma unroll
    for (int j = 0; j < 4; ++j) {
        uint4 p;
        p.x = pack_split(e[0][j]); p.y = pack_split(e[1][j]);
        p.z = pack_split(e[2][j]); p.w = pack_split(e[3][j]);
        *(uint4*)&dst[(4 * cb + j) * sd + k0] = p;
    }
}

__global__ __launch_bounds__(256, 2)
void made_flow_r9(const float* __restrict__ inputs,
                  const float* __restrict__ W1,
                  const float* __restrict__ W2,
                  const float* __restrict__ Wout,
                  const int* __restrict__ idx,
                  const int* __restrict__ valid,
                  const int* __restrict__ M1,
                  const int* __restrict__ M2,
                  const int* __restrict__ Mout,
                  float* __restrict__ out)
{
    __shared__ __align__(16) char regA[TROWS * SHP * 2 * 2];  // h1 hi/lo | scratch (17408 B)
    __shared__ __align__(16) char regB[TROWS * SHP * 2 * 2];  // h2 hi/lo (17408 B)
    __shared__ __align__(16) u16  xgh[2][TROWS * SXG];        // 5120 B
    __shared__ __align__(16) u16  xgl[2][TROWS * SXG];        // 5120 B
    __shared__ __align__(16) float xgf[2][TROWS * SXF];       // 9728 B
    __shared__ __align__(16) float red_all[TILES_PER_BLOCK][TROWS][4];  // 8192 B
    __shared__ int   idx_s[RR];
    __shared__ float v_s[RR];

    u16* const h1h = (u16*)regA;
    u16* const h1l = h1h + TROWS * SHP;
    u32* const scr = (u32*)regA;
    u16* const h2h = (u16*)regB;
    u16* const h2l = h2h + TROWS * SHP;

    const int tid  = threadIdx.x;
    const int r    = blockIdx.x / BLOCKS_PER_R;
    const int rb   = blockIdx.x % BLOCKS_PER_R;
    const int lane = tid & 63;
    const int wave = tid >> 6;
    const int q    = lane >> 4;
    const int l16  = lane & 15;

    if (tid < RR) {
        idx_s[tid] = idx[r * RR + tid];
        v_s[tid]   = valid[r * RR + tid] ? 1.f : 0.f;
    }

    // ---- stage all weights -> per-wave register A-frags (W^T) via LDS scratch ----
    bf16x8_t a1h[2], a1l[2];        // W1^T: wave cols 32w+16mi+l16, k=q*8..
    bf16x8_t a2h[2][4], a2l[2][4];  // W2^T: [mi][ks]
    bf16x8_t aoh[4],    aol[4];     // Wout^T: wave cols 16w+l16, [ks]
    {
        const float* W1r = W1 + r * RR * HH;   const int* M1r = M1 + r * RR * HH;
        const float* W2r = W2 + r * HH * HH;   const int* M2r = M2 + r * HH * HH;
        const float* Wor = Wout + r * HH * OO; const int* Mor = Mout + r * HH * OO;
        for (int c = 0; c < 4; ++c) {
            __syncthreads();
            stage_block(W2r, M2r, HH, 32 * c, HH, scr, SSC, tid);
            __syncthreads();
            if (wave == c) {
#pragma unroll
                for (int mi = 0; mi < 2; ++mi)
#pragma unroll
                    for (int ks = 0; ks < 4; ++ks)
                        unpack8(&scr[(16 * mi + l16) * SSC + ks * 32 + q * 8],
                                a2h[mi][ks], a2l[mi][ks]);
            }
        }
        for (int c = 0; c < 2; ++c) {
            __syncthreads();
            stage_block(Wor, Mor, OO, 32 * c, HH, scr, SSC, tid);
            __syncthreads();
            if ((wave >> 1) == c) {
                const int nl = wave & 1;
#pragma unroll
                for (int ks = 0; ks < 4; ++ks)
                    unpack8(&scr[(16 * nl + l16) * SSC + ks * 32 + q * 8],
                            aoh[ks], aol[ks]);
            }
        }
        for (int c = 0; c < 4; ++c) {
            __syncthreads();
            stage_block(W1r, M1r, HH, 32 * c, RR, scr, SSC, tid);  // K=32
            __syncthreads();
            if (wave == c) {
#pragma unroll
                for (int mi = 0; mi < 2; ++mi)
                    unpack8(&scr[(16 * mi + l16) * SSC + q * 8], a1h[mi], a1l[mi]);
            }
        }
    }
    __syncthreads();   // scratch reads done before h1 writes

    const f32x4_t zero4 = {0.f, 0.f, 0.f, 0.f};
    const int grow = tid >> 3, gg = tid & 7;

    // ---- prologue: gather(0) ----
    {
        const int base = (rb * TILES_PER_BLOCK * TROWS + grow) * DD;
        float gx[4];
#pragma unroll
        for (int u = 0; u < 4; ++u)
            gx[u] = inputs[base + idx_s[4 * gg + u]] * v_s[4 * gg + u];
        ushort4 gh, gl;
        gh.x = bf16_rne(gx[0]); gl.x = lo_trunc(gx[0], gh.x);
        gh.y = bf16_rne(gx[1]); gl.y = lo_trunc(gx[1], gh.y);
        gh.z = bf16_rne(gx[2]); gl.z = lo_trunc(gx[2], gh.z);
        gh.w = bf16_rne(gx[3]); gl.w = lo_trunc(gx[3], gh.w);
        *(ushort4*)&xgh[0][grow * SXG + 4 * gg] = gh;
        *(ushort4*)&xgl[0][grow * SXG + 4 * gg] = gl;
        *(float2*)&xgf[0][grow * SXF + 4 * gg]     = make_float2(gx[0], gx[1]);
        *(float2*)&xgf[0][grow * SXF + 4 * gg + 2] = make_float2(gx[2], gx[3]);
    }
    __syncthreads();

    // ---- prologue: P1(0): h1^T = W1^T @ xg^T ----
    {
        bf16x8_t bh[2], bl[2];
#pragma unroll
        for (int ni = 0; ni < 2; ++ni) {
            bh[ni] = *(const bf16x8_t*)&xgh[0][(16 * ni + l16) * SXG + q * 8];
            bl[ni] = *(const bf16x8_t*)&xgl[0][(16 * ni + l16) * SXG + q * 8];
        }
#pragma unroll
        for (int mi = 0; mi < 2; ++mi)
#pragma unroll
            for (int ni = 0; ni < 2; ++ni) {
                f32x4_t a = zero4;
                a = mfma16(a1h[mi], bh[ni], a);
                a = mfma16(a1l[mi], bh[ni], a);
                a = mfma16(a1h[mi], bl[ni], a);
                // C: row_c = c1 = 32w+16mi+4q+i, col_c = batchrow = 16ni+l16
                ushort4 vh, vl;
                float v0 = fmaxf(a[0], 0.f), v1 = fmaxf(a[1], 0.f);
                float v2 = fmaxf(a[2], 0.f), v3 = fmaxf(a[3], 0.f);
                vh.x = bf16_rne(v0); vl.x = lo_trunc(v0, vh.x);
                vh.y = bf16_rne(v1); vl.y = lo_trunc(v1, vh.y);
                vh.z = bf16_rne(v2); vl.z = lo_trunc(v2, vh.z);
                vh.w = bf16_rne(v3); vl.w = lo_trunc(v3, vh.w);
                const int o = (16 * ni + l16) * SHP + 32 * wave + 16 * mi + 4 * q;
                *(ushort4*)&h1h[o] = vh;
                *(ushort4*)&h1l[o] = vl;
            }
    }

    for (int t = 0; t < TILES_PER_BLOCK; ++t) {
        const int row0 = (rb * TILES_PER_BLOCK + t) * TROWS;
        __syncthreads();   // head barrier

        // ========== interval A: gather-issue(t+1) + P2(t) + gather-store(t+1) =====
        float gx[4];
        const bool dg = (t + 1 < TILES_PER_BLOCK);
        if (dg) {
            const int base = (row0 + TROWS + grow) * DD;
#pragma unroll
            for (int u = 0; u < 4; ++u)
                gx[u] = inputs[base + idx_s[4 * gg + u]] * v_s[4 * gg + u];
        }
        {
            // P2: h2^T = W2^T @ h1^T   (M=128 cols, N=32 rows, K=128)
            f32x4_t acc[2][2] = {{zero4, zero4}, {zero4, zero4}};
#pragma unroll
            for (int ks = 0; ks < 4; ++ks) {
#pragma unroll
                for (int ni = 0; ni < 2; ++ni) {
                    bf16x8_t bh = *(const bf16x8_t*)&h1h[(16 * ni + l16) * SHP + ks * 32 + q * 8];
                    bf16x8_t bl = *(const bf16x8_t*)&h1l[(16 * ni + l16) * SHP + ks * 32 + q * 8];
#pragma unroll
                    for (int mi = 0; mi < 2; ++mi) {
                        f32x4_t a = acc[mi][ni];
                        a = mfma16(a2h[mi][ks], bh, a);
                        a = mfma16(a2l[mi][ks], bh, a);
                        a = mfma16(a2h[mi][ks], bl, a);
                        acc[mi][ni] = a;
                    }
                }
            }
            if (dg) {
                const int b = (t + 1) & 1;
                ushort4 gh, gl;
                gh.x = bf16_rne(gx[0]); gl.x = lo_trunc(gx[0], gh.x);
                gh.y = bf16_rne(gx[1]); gl.y = lo_trunc(gx[1], gh.y);
                gh.z = bf16_rne(gx[2]); gl.z = lo_trunc(gx[2], gh.z);
                gh.w = bf16_rne(gx[3]); gl.w = lo_trunc(gx[3], gh.w);
                *(ushort4*)&xgh[b][grow * SXG + 4 * gg] = gh;
                *(ushort4*)&xgl[b][grow * SXG + 4 * gg] = gl;
                *(float2*)&xgf[b][grow * SXF + 4 * gg]     = make_float2(gx[0], gx[1]);
                *(float2*)&xgf[b][grow * SXF + 4 * gg + 2] = make_float2(gx[2], gx[3]);
            }
#pragma unroll
            for (int mi = 0; mi < 2; ++mi)
#pragma unroll
                for (int ni = 0; ni < 2; ++ni) {
                    ushort4 vh, vl;
                    float v0 = fmaxf(acc[mi][ni][0], 0.f), v1 = fmaxf(acc[mi][ni][1], 0.f);
                    float v2 = fmaxf(acc[mi][ni][2], 0.f), v3 = fmaxf(acc[mi][ni][3], 0.f);
                    vh.x = bf16_rne(v0); vl.x = lo_trunc(v0, vh.x);
                    vh.y = bf16_rne(v1); vl.y = lo_trunc(v1, vh.y);
                    vh.z = bf16_rne(v2); vl.z = lo_trunc(v2, vh.z);
                    vh.w = bf16_rne(v3); vl.w = lo_trunc(v3, vh.w);
                    const int o = (16 * ni + l16) * SHP + 32 * wave + 16 * mi + 4 * q;
                    *(ushort4*)&h2h[o] = vh;
                    *(ushort4*)&h2l[o] = vl;
                }
        }
        __syncthreads();   // mid barrier

        // ========== interval B: P3(t) + P1(t+1) + epilogue(t) =====================
        // P3: out^T = Wout^T @ h2^T  (M=64, N=32, K=128); wave w: o = 16w+4q+i
        f32x4_t acc3[2] = {zero4, zero4};
#pragma unroll
        for (int ks = 0; ks < 4; ++ks) {
#pragma unroll
            for (int ni = 0; ni < 2; ++ni) {
                bf16x8_t bh = *(const bf16x8_t*)&h2h[(16 * ni + l16) * SHP + ks * 32 + q * 8];
                bf16x8_t bl = *(const bf16x8_t*)&h2l[(16 * ni + l16) * SHP + ks * 32 + q * 8];
                f32x4_t a = acc3[ni];
                a = mfma16(aoh[ks], bh, a);
                a = mfma16(aol[ks], bh, a);
                a = mfma16(aoh[ks], bl, a);
                acc3[ni] = a;
            }
        }

        if (dg) {   // P1(t+1)
            const int b = (t + 1) & 1;
            bf16x8_t bh[2], bl[2];
#pragma unroll
            for (int ni = 0; ni < 2; ++ni) {
                bh[ni] = *(const bf16x8_t*)&xgh[b][(16 * ni + l16) * SXG + q * 8];
                bl[ni] = *(const bf16x8_t*)&xgl[b][(16 * ni + l16) * SXG + q * 8];
            }
#pragma unroll
            for (int mi = 0; mi < 2; ++mi)
#pragma unroll
                for (int ni = 0; ni < 2; ++ni) {
                    f32x4_t a = zero4;
                    a = mfma16(a1h[mi], bh[ni], a);
                    a = mfma16(a1l[mi], bh[ni], a);
                    a = mfma16(a1h[mi], bl[ni], a);
                    ushort4 vh, vl;
                    float v0 = fmaxf(a[0], 0.f), v1 = fmaxf(a[1], 0.f);
                    float v2 = fmaxf(a[2], 0.f), v3 = fmaxf(a[3], 0.f);
                    vh.x = bf16_rne(v0); vl.x = lo_trunc(v0, vh.x);
                    vh.y = bf16_rne(v1); vl.y = lo_trunc(v1, vh.y);
                    vh.z = bf16_rne(v2); vl.z = lo_trunc(v2, vh.z);
                    vh.w = bf16_rne(v3); vl.w = lo_trunc(v3, vh.w);
                    const int o = (16 * ni + l16) * SHP + 32 * wave + 16 * mi + 4 * q;
                    *(ushort4*)&h1h[o] = vh;
                    *(ushort4*)&h1l[o] = vl;
                }
        }

        {   // epilogue(t): acc3[ni][i] = out^T[o=16w+4q+i][row=16ni+l16]
            // i even -> shift(j), i odd -> log_s(j), j = 8w+2q+(i>>1)
            const int j0 = 8 * wave + 2 * q;
            const float vj0 = v_s[j0], vj1 = v_s[j0 + 1];
            float p[2];
#pragma unroll
            for (int ni = 0; ni < 2; ++ni) {
                const int row = 16 * ni + l16;
                float2 xv = *(const float2*)&xgf[t & 1][row * SXF + j0];
                const float u0 = (xv.x - acc3[ni][0]) * __expf(-acc3[ni][1]);
                const float u1 = (xv.y - acc3[ni][2]) * __expf(-acc3[ni][3]);
                p[ni] = (-0.5f * u0 * u0 - 0.91893853320467266954f - acc3[ni][1]) * vj0
                      + (-0.5f * u1 * u1 - 0.91893853320467266954f - acc3[ni][3]) * vj1;
            }
#pragma unroll
            for (int ni = 0; ni < 2; ++ni) {
                p[ni] += __shfl_xor(p[ni], 16, 64);
                p[ni] += __shfl_xor(p[ni], 32, 64);
            }
            if (q == 0) {
#pragma unroll
                for (int ni = 0; ni < 2; ++ni)
                    red_all[t][16 * ni + l16][wave] = p[ni];
            }
        }
    }

    // ---- tail: reduce red_all across waves, single batched global store ----
    __syncthreads();
#pragma unroll
    for (int rep = 0; rep < 2; ++rep) {
        const int f   = tid + rep * 256;       // 0..511
        const int tt  = f >> 5;
        const int row = f & 31;
        float4 rv = *(const float4*)&red_all[tt][row][0];
        out[((rb * TILES_PER_BLOCK + tt) * TROWS + row) * RR + r] =
            rv.x + rv.y + rv.z + rv.w;
    }
}

extern "C" void kernel_launch(void* const* d_in, const int* in_sizes, int n_in,
                              void* d_out, int out_size, void* d_ws, size_t ws_size,
                              hipStream_t stream)
{
    const float* inputs = (const float*)d_in[0];
    const float* W1     = (const float*)d_in[1];
    const float* W2     = (const float*)d_in[2];
    const float* Wout   = (const float*)d_in[3];
    const int*   idx    = (const int*)d_in[4];
    const int*   valid  = (const int*)d_in[5];
    const int*   M1     = (const int*)d_in[6];
    const int*   M2     = (const int*)d_in[7];
    const int*   Mout   = (const int*)d_in[8];
    float*       out    = (float*)d_out;

    hipLaunchKernelGGL(made_flow_r9, dim3(RR * BLOCKS_PER_R), dim3(256), 0, stream,
                       inputs, W1, W2, Wout, idx, valid, M1, M2, Mout, out);
}